// Round 1
// baseline (1501.395 us; speedup 1.0000x reference)
//
#include <hip/hip_runtime.h>
#include <cstdint>
#include <cstddef>

// Problem constants
static constexpr int Bn   = 4;
static constexpr int Sn   = 4096;
static constexpr int Hn   = 2048;
static constexpr int CINn = 4096;
static constexpr int COUTn= 4096;
static constexpr int Gn   = 8;
static constexpr int GCn  = 512;    // CIN/G
static constexpr int Kt   = 4;      // conv taps
static constexpr int Mn   = Bn * Sn;   // 16384
static constexpr int SPn  = Sn + 3;    // padded rows per batch (3 zero rows in front)

typedef _Float16 half8 __attribute__((ext_vector_type(8)));
typedef _Float16 half4 __attribute__((ext_vector_type(4)));
typedef float    floatx4 __attribute__((ext_vector_type(4)));

// ---------------- prep kernels ----------------

__global__ void cvt_f32_f16(const float* __restrict__ src, _Float16* __restrict__ dst, int n4) {
    int i = blockIdx.x * blockDim.x + threadIdx.x;
    if (i < n4) {
        float4 v = ((const float4*)src)[i];
        half4 h;
        h[0] = (_Float16)v.x; h[1] = (_Float16)v.y;
        h[2] = (_Float16)v.z; h[3] = (_Float16)v.w;
        ((half4*)dst)[i] = h;
    }
}

// conv_w [COUT, 512, 4] fp32 -> Wc [COUT, k*512 + ci] fp16
__global__ void cvt_convw(const float* __restrict__ src, _Float16* __restrict__ dst) {
    int t = blockIdx.x * blockDim.x + threadIdx.x;   // 0 .. 4096*512
    int co = t >> 9, ci = t & 511;
    float4 v = ((const float4*)src)[(co << 9) + ci]; // src[co][ci][0..3] contiguous
    size_t base = (size_t)co * 2048 + ci;
    dst[base]        = (_Float16)v.x;
    dst[base + 512]  = (_Float16)v.y;
    dst[base + 1024] = (_Float16)v.z;
    dst[base + 1536] = (_Float16)v.w;
}

// zero the 3 leading pad rows of each batch in Hp [B*(S+3), 4096]
__global__ void zero_pads(_Float16* __restrict__ Hp) {
    int t = blockIdx.x * blockDim.x + threadIdx.x;   // 4 * 3*4096 = 49152
    int b = t / (3 * CINn);
    int off = t - b * (3 * CINn);
    Hp[(size_t)b * SPn * CINn + off] = (_Float16)0.f;
}

// ---------------- GEMM (m97 structure) ----------------
// C[m,n] = sum_k A[m,k]*B[n,k]  (B^T layout: K contiguous in both operands)
// MODE 0: stage1  A=Xh[16384,2048]          out: Hp fp16, padded rows, +b_in
// MODE 1: stage2  A=Hp (shifted conv gather) out: Yh fp16, +conv_b, SiLU
// MODE 2: stage3  A=Yh[16384,4096]          out: fp32, +b_out

__device__ __forceinline__ void async16(const void* g, void* l) {
    __builtin_amdgcn_global_load_lds(
        (__attribute__((address_space(1))) void*)(g),
        (__attribute__((address_space(3))) void*)(l),
        16, 0, 0);
}

template <int MODE>
__global__ __launch_bounds__(256) void gemm_k(
    const _Float16* __restrict__ A,
    const _Float16* __restrict__ Bw,
    const float* __restrict__ bias,
    void* __restrict__ outp,
    int Kd, int Ntiles)
{
    __shared__ __align__(16) _Float16 As[128 * 32];  // 8 KB
    __shared__ __align__(16) _Float16 Bs[128 * 32];  // 8 KB

    const int t  = threadIdx.x;
    const int w  = t >> 6;        // wave 0..3
    const int l  = t & 63;        // lane
    const int mt = blockIdx.x / Ntiles;
    const int nt = blockIdx.x % Ntiles;
    const int m0 = mt * 128, n0 = nt * 128;

    // --- staging addresses (slot t -> row t/4, 8-elem col block t%4) ---
    const int r0 = t >> 2;
    const int cb = (t & 3) * 8;
    const _Float16 *pa0, *pa1;
    if (MODE == 1) {
        // A row for (m, tap k): b*(S+3) + s + k ; col: g*512 + (kk&511)
        int ma0 = m0 + r0, ma1 = m0 + r0 + 64;
        int g = n0 >> 9;
        pa0 = A + ((size_t)((ma0 >> 12) * SPn + (ma0 & 4095)) << 12) + g * 512 + cb;
        pa1 = A + ((size_t)((ma1 >> 12) * SPn + (ma1 & 4095)) << 12) + g * 512 + cb;
    } else {
        pa0 = A + (size_t)(m0 + r0) * Kd + cb;
        pa1 = A + (size_t)(m0 + r0 + 64) * Kd + cb;
    }
    const _Float16* pb0 = Bw + (size_t)(n0 + r0) * Kd + cb;
    const _Float16* pb1 = Bw + (size_t)(n0 + r0 + 64) * Kd + cb;

    // wave-uniform LDS bases (lane data lands at base + lane*16B)
    _Float16* lA0 = As + w * 512;
    _Float16* lA1 = As + 2048 + w * 512;
    _Float16* lB0 = Bs + w * 512;
    _Float16* lB1 = Bs + 2048 + w * 512;

    floatx4 acc[4][4] = {};

    const int arow = (w & 1) * 64;
    const int brow = (w >> 1) * 64;
    const int fr   = l & 15;
    const int koff = (l >> 4) * 8;

    const int niter = Kd >> 5;
    for (int kt = 0; kt < niter; ++kt) {
        const int kk0 = kt << 5;
        int aoff = kk0;
        if (MODE == 1) aoff += (kk0 >> 9) * 3584;  // (row += k) - k*512 cols
        async16(pa0 + aoff, lA0);
        async16(pa1 + aoff, lA1);
        async16(pb0 + kk0, lB0);
        async16(pb1 + kk0, lB1);
        __syncthreads();   // drains vmcnt(0): LDS tiles ready

        half8 af[4], bfr[4];
        #pragma unroll
        for (int i = 0; i < 4; ++i)
            af[i] = *(const half8*)(As + (arow + i * 16 + fr) * 32 + koff);
        #pragma unroll
        for (int j = 0; j < 4; ++j)
            bfr[j] = *(const half8*)(Bs + (brow + j * 16 + fr) * 32 + koff);
        #pragma unroll
        for (int i = 0; i < 4; ++i)
            #pragma unroll
            for (int j = 0; j < 4; ++j)
                acc[i][j] = __builtin_amdgcn_mfma_f32_16x16x32_f16(af[i], bfr[j], acc[i][j], 0, 0, 0);
        __syncthreads();   // all reads done before next stage overwrites
    }

    // --- epilogue: D[row=(l>>4)*4+r][col=l&15] per 16x16 subtile ---
    #pragma unroll
    for (int j = 0; j < 4; ++j) {
        int ncol = n0 + brow + j * 16 + fr;
        float bv = bias[ncol];
        #pragma unroll
        for (int i = 0; i < 4; ++i) {
            int mbase = m0 + arow + i * 16 + (l >> 4) * 4;
            #pragma unroll
            for (int r = 0; r < 4; ++r) {
                int m = mbase + r;
                float v = acc[i][j][r] + bv;
                if (MODE == 0) {
                    size_t row = (size_t)((m >> 12) * SPn + 3 + (m & 4095));
                    ((_Float16*)outp)[(row << 12) + ncol] = (_Float16)v;
                } else if (MODE == 1) {
                    v = v * (1.0f / (1.0f + __expf(-v)));   // SiLU
                    ((_Float16*)outp)[((size_t)m << 12) + ncol] = (_Float16)v;
                } else {
                    ((float*)outp)[((size_t)m << 11) + ncol] = v;
                }
            }
        }
    }
}

// ---------------- launch ----------------

extern "C" void kernel_launch(void* const* d_in, const int* in_sizes, int n_in,
                              void* d_out, int out_size, void* d_ws, size_t ws_size,
                              hipStream_t stream) {
    const float* x      = (const float*)d_in[0];
    const float* W_in   = (const float*)d_in[1];
    const float* b_in   = (const float*)d_in[2];
    const float* conv_w = (const float*)d_in[3];
    const float* conv_b = (const float*)d_in[4];
    const float* W_out  = (const float*)d_in[5];
    const float* b_out  = (const float*)d_in[6];
    float* out = (float*)d_out;

    // workspace layout (bytes) — total ~368 MB
    char* ws = (char*)d_ws;
    _Float16* Xh  = (_Float16*)(ws);                         //  67,108,864  x fp16 [16384,2048]
    _Float16* W1h = (_Float16*)(ws + 67108864);              //  16,777,216  W_in fp16 [4096,2048]
    _Float16* Wch = (_Float16*)(ws + 83886080);              //  16,777,216  conv_w fp16 [4096,2048]
    _Float16* W2h = (_Float16*)(ws + 100663296);             //  16,777,216  W_out fp16 [2048,4096]
    _Float16* Hp  = (_Float16*)(ws + 117440512);             // 134,316,032  h fp16 [4*(4096+3),4096]
    _Float16* Yh  = (_Float16*)(ws + 251756544);             // 134,217,728  y fp16 [16384,4096]
    (void)ws_size; (void)in_sizes; (void)n_in; (void)out_size;

    cvt_f32_f16<<<32768, 256, 0, stream>>>(x,     Xh,  Mn * Hn / 4);        // 8,388,608 float4s
    cvt_f32_f16<<<8192,  256, 0, stream>>>(W_in,  W1h, CINn * Hn / 4);      // 2,097,152
    cvt_convw <<<8192,  256, 0, stream>>>(conv_w, Wch);                     // 4096*512 threads
    cvt_f32_f16<<<8192,  256, 0, stream>>>(W_out, W2h, Hn * COUTn / 4);     // 2,097,152
    zero_pads <<<192,   256, 0, stream>>>(Hp);                              // 49,152 elems

    // stage 1: h = x @ W_in^T + b_in        -> Hp (padded, fp16)
    gemm_k<0><<<(Mn / 128) * (CINn / 128), 256, 0, stream>>>(Xh, W1h, b_in, (void*)Hp, Hn, CINn / 128);
    // stage 2: y = silu(causal_gconv(h) + conv_b) -> Yh (fp16)
    gemm_k<1><<<(Mn / 128) * (COUTn / 128), 256, 0, stream>>>(Hp, Wch, conv_b, (void*)Yh, GCn * Kt, COUTn / 128);
    // stage 3: out = y @ W_out^T + b_out    -> fp32
    gemm_k<2><<<(Mn / 128) * (Hn / 128), 256, 0, stream>>>(Yh, W2h, b_out, (void*)out, COUTn, Hn / 128);
}

// Round 2
// 1441.978 us; speedup vs baseline: 1.0412x; 1.0412x over previous
//
#include <hip/hip_runtime.h>
#include <cstdint>
#include <cstddef>

// Problem constants
static constexpr int Bn   = 4;
static constexpr int Sn   = 4096;
static constexpr int Hn   = 2048;
static constexpr int CINn = 4096;
static constexpr int COUTn= 4096;
static constexpr int Gn   = 8;
static constexpr int GCn  = 512;    // CIN/G
static constexpr int Kt   = 4;      // conv taps
static constexpr int Mn   = Bn * Sn;   // 16384
static constexpr int SPn  = Sn + 3;    // padded rows per batch (3 zero rows in front)

typedef _Float16 half8 __attribute__((ext_vector_type(8)));
typedef _Float16 half4 __attribute__((ext_vector_type(4)));
typedef float    floatx4 __attribute__((ext_vector_type(4)));

// ---------------- prep kernels ----------------

__global__ void cvt_f32_f16(const float* __restrict__ src, _Float16* __restrict__ dst, int n4) {
    int i = blockIdx.x * blockDim.x + threadIdx.x;
    if (i < n4) {
        float4 v = ((const float4*)src)[i];
        half4 h;
        h[0] = (_Float16)v.x; h[1] = (_Float16)v.y;
        h[2] = (_Float16)v.z; h[3] = (_Float16)v.w;
        ((half4*)dst)[i] = h;
    }
}

// conv_w [COUT, 512, 4] fp32 -> Wc [COUT, k*512 + ci] fp16
__global__ void cvt_convw(const float* __restrict__ src, _Float16* __restrict__ dst) {
    int t = blockIdx.x * blockDim.x + threadIdx.x;   // 0 .. 4096*512
    int co = t >> 9, ci = t & 511;
    float4 v = ((const float4*)src)[(co << 9) + ci]; // src[co][ci][0..3] contiguous
    size_t base = (size_t)co * 2048 + ci;
    dst[base]        = (_Float16)v.x;
    dst[base + 512]  = (_Float16)v.y;
    dst[base + 1024] = (_Float16)v.z;
    dst[base + 1536] = (_Float16)v.w;
}

// zero the 3 leading pad rows of each batch in Hp [B*(S+3), 4096]
__global__ void zero_pads(_Float16* __restrict__ Hp) {
    int t = blockIdx.x * blockDim.x + threadIdx.x;   // 4 * 3*4096 = 49152
    int b = t / (3 * CINn);
    int off = t - b * (3 * CINn);
    Hp[(size_t)b * SPn * CINn + off] = (_Float16)0.f;
}

// ---------------- GEMM (m97 structure, BK=64, XOR-swizzled LDS) ----------------
// C[m,n] = sum_k A[m,k]*B[n,k]  (B^T layout: K contiguous in both operands)
// MODE 0: stage1  A=Xh[16384,2048]           out: Hp fp16, padded rows, +b_in
// MODE 1: stage2  A=Hp (shifted conv gather)  out: Yh fp16, +conv_b, SiLU
// MODE 2: stage3  A=Yh[16384,4096]           out: fp32, +b_out
//
// LDS tile: [128 rows][64 cols] fp16 per operand (16 KB each, 32 KB total).
// Staging: 4 async16 loads per wave per operand; slot t -> row t>>3,
// col-block (t&7) XOR (row&7)  (swizzle applied at the GLOBAL source address,
// since global_load_lds lands lane data at wave-base + lane*16B and cannot
// scatter). Fragment reads de-swizzle: block = (ks/8 + quad) ^ (row&7) ->
// bank groups spread evenly, conflicts at the free 2-way floor (m136).

__device__ __forceinline__ void async16(const void* g, void* l) {
    __builtin_amdgcn_global_load_lds(
        (__attribute__((address_space(1))) void*)(g),
        (__attribute__((address_space(3))) void*)(l),
        16, 0, 0);
}

template <int MODE>
__global__ __launch_bounds__(256) void gemm_k(
    const _Float16* __restrict__ A,
    const _Float16* __restrict__ Bw,
    const float* __restrict__ bias,
    void* __restrict__ outp,
    int Kd, int Ntiles)
{
    __shared__ __align__(16) _Float16 As[128 * 64];  // 16 KB
    __shared__ __align__(16) _Float16 Bs[128 * 64];  // 16 KB

    const int t  = threadIdx.x;
    const int w  = t >> 6;        // wave 0..3
    const int l  = t & 63;        // lane
    const int mt = blockIdx.x / Ntiles;
    const int nt = blockIdx.x % Ntiles;
    const int m0 = mt * 128, n0 = nt * 128;

    // --- staging addresses: slot t -> row (q*32 + t>>3), swizzled col block ---
    const int sr  = t >> 3;                       // 0..31
    const int scb = (((t & 7) ^ (sr & 7)) << 3);  // swizzled col in fp16 units
    const _Float16* pa[4];
    const _Float16* pb[4];
    #pragma unroll
    for (int q = 0; q < 4; ++q) {
        int ma = m0 + q * 32 + sr;
        if (MODE == 1) {
            // A row for (m, tap k): b*(S+3) + 3 + (s-3) + k ; col: g*512 + ci
            int g = n0 >> 9;
            pa[q] = A + ((size_t)((ma >> 12) * SPn + (ma & 4095)) << 12) + g * 512 + scb;
        } else {
            pa[q] = A + (size_t)ma * Kd + scb;
        }
        pb[q] = Bw + (size_t)(n0 + q * 32 + sr) * Kd + scb;
    }

    // wave-uniform LDS bases (lane data lands at base + lane*16B)
    const int wbase = w * 512;    // fp16 elems: w*64 lanes * 8 elems

    floatx4 acc[4][4] = {};

    const int arow = (w & 1) * 64;
    const int brow = (w >> 1) * 64;
    const int fr   = l & 15;
    const int quad = l >> 4;
    const int sw   = fr & 7;      // de-swizzle key = row&7

    const int niter = Kd >> 6;
    for (int kt = 0; kt < niter; ++kt) {
        const int kk0 = kt << 6;
        int aoff = kk0;
        if (MODE == 1) aoff += (kk0 >> 9) * 3584;  // (row += tap) - tap*512 cols
        #pragma unroll
        for (int q = 0; q < 4; ++q) async16(pa[q] + aoff, As + q * 2048 + wbase);
        #pragma unroll
        for (int q = 0; q < 4; ++q) async16(pb[q] + kk0,  Bs + q * 2048 + wbase);
        __syncthreads();   // drains vmcnt(0): LDS tiles ready

        #pragma unroll
        for (int ks = 0; ks < 2; ++ks) {
            half8 af[4], bfr[4];
            #pragma unroll
            for (int i = 0; i < 4; ++i)
                af[i] = *(const half8*)(As + (arow + i * 16 + fr) * 64
                                           + ((((ks << 2) + quad) ^ sw) << 3));
            #pragma unroll
            for (int j = 0; j < 4; ++j)
                bfr[j] = *(const half8*)(Bs + (brow + j * 16 + fr) * 64
                                            + ((((ks << 2) + quad) ^ sw) << 3));
            #pragma unroll
            for (int i = 0; i < 4; ++i)
                #pragma unroll
                for (int j = 0; j < 4; ++j)
                    acc[i][j] = __builtin_amdgcn_mfma_f32_16x16x32_f16(af[i], bfr[j], acc[i][j], 0, 0, 0);
        }
        __syncthreads();   // all reads done before next stage overwrites
    }

    // --- epilogue: D[row=(l>>4)*4+r][col=l&15] per 16x16 subtile ---
    #pragma unroll
    for (int j = 0; j < 4; ++j) {
        int ncol = n0 + brow + j * 16 + fr;
        float bv = bias[ncol];
        #pragma unroll
        for (int i = 0; i < 4; ++i) {
            int mbase = m0 + arow + i * 16 + quad * 4;
            #pragma unroll
            for (int r = 0; r < 4; ++r) {
                int m = mbase + r;
                float v = acc[i][j][r] + bv;
                if (MODE == 0) {
                    size_t row = (size_t)((m >> 12) * SPn + 3 + (m & 4095));
                    ((_Float16*)outp)[(row << 12) + ncol] = (_Float16)v;
                } else if (MODE == 1) {
                    v = v * (1.0f / (1.0f + __expf(-v)));   // SiLU
                    ((_Float16*)outp)[((size_t)m << 12) + ncol] = (_Float16)v;
                } else {
                    ((float*)outp)[((size_t)m << 11) + ncol] = v;
                }
            }
        }
    }
}

// ---------------- launch ----------------

extern "C" void kernel_launch(void* const* d_in, const int* in_sizes, int n_in,
                              void* d_out, int out_size, void* d_ws, size_t ws_size,
                              hipStream_t stream) {
    const float* x      = (const float*)d_in[0];
    const float* W_in   = (const float*)d_in[1];
    const float* b_in   = (const float*)d_in[2];
    const float* conv_w = (const float*)d_in[3];
    const float* conv_b = (const float*)d_in[4];
    const float* W_out  = (const float*)d_in[5];
    const float* b_out  = (const float*)d_in[6];
    float* out = (float*)d_out;

    // workspace layout (bytes) — total ~368 MB
    char* ws = (char*)d_ws;
    _Float16* Xh  = (_Float16*)(ws);                         //  67,108,864  x fp16 [16384,2048]
    _Float16* W1h = (_Float16*)(ws + 67108864);              //  16,777,216  W_in fp16 [4096,2048]
    _Float16* Wch = (_Float16*)(ws + 83886080);              //  16,777,216  conv_w fp16 [4096,2048]
    _Float16* W2h = (_Float16*)(ws + 100663296);             //  16,777,216  W_out fp16 [2048,4096]
    _Float16* Hp  = (_Float16*)(ws + 117440512);             // 134,316,032  h fp16 [4*(4096+3),4096]
    _Float16* Yh  = (_Float16*)(ws + 251756544);             // 134,217,728  y fp16 [16384,4096]
    (void)ws_size; (void)in_sizes; (void)n_in; (void)out_size;

    cvt_f32_f16<<<32768, 256, 0, stream>>>(x,     Xh,  Mn * Hn / 4);        // 8,388,608 float4s
    cvt_f32_f16<<<8192,  256, 0, stream>>>(W_in,  W1h, CINn * Hn / 4);      // 2,097,152
    cvt_convw <<<8192,  256, 0, stream>>>(conv_w, Wch);                     // 4096*512 threads
    cvt_f32_f16<<<8192,  256, 0, stream>>>(W_out, W2h, Hn * COUTn / 4);     // 2,097,152
    zero_pads <<<192,   256, 0, stream>>>(Hp);                              // 49,152 elems

    // stage 1: h = x @ W_in^T + b_in        -> Hp (padded, fp16)
    gemm_k<0><<<(Mn / 128) * (CINn / 128), 256, 0, stream>>>(Xh, W1h, b_in, (void*)Hp, Hn, CINn / 128);
    // stage 2: y = silu(causal_gconv(h) + conv_b) -> Yh (fp16)
    gemm_k<1><<<(Mn / 128) * (COUTn / 128), 256, 0, stream>>>(Hp, Wch, conv_b, (void*)Yh, GCn * Kt, COUTn / 128);
    // stage 3: out = y @ W_out^T + b_out    -> fp32
    gemm_k<2><<<(Mn / 128) * (Hn / 128), 256, 0, stream>>>(Yh, W2h, b_out, (void*)out, COUTn, Hn / 128);
}